// Round 2
// baseline (15235.242 us; speedup 1.0000x reference)
//
#include <hip/hip_runtime.h>
#include <hip/hip_bf16.h>
#include <stdint.h>

#define T_LEN 4096
#define D_DIM 256
#define HDIM 256
#define G4 1024          // 4*HD gate rows per direction
#define NTAGS 32
#define START_TAG 30
#define STOP_TAG 31

typedef unsigned long long u64;
typedef unsigned int u32;
typedef float v2f __attribute__((ext_vector_type(2)));

__device__ __forceinline__ float sigf(float x){ return 1.0f/(1.0f+expf(-x)); }

// Coherent (system-scope) 8B load: bypasses L1/L2 (sc0 sc1), COALESCES across
// lanes (unlike per-lane atomic loads). Used for cross-XCD h polling.
__device__ __forceinline__ u64 ld_u64_sys(const u64* p){
    u64 v;
    asm volatile("global_load_dwordx2 %0, %1, off sc0 sc1\n\t"
                 "s_waitcnt vmcnt(0)"
                 : "=v"(v) : "v"(p) : "memory");
    return v;
}

// ---------------------------------------------------------------------------
// K1: embedding gather + input projections xg = E[seq] @ Wih^T + (bih+bhh)
// ---------------------------------------------------------------------------
__global__ __launch_bounds__(256) void k_xg(const int* __restrict__ seq,
    const float* __restrict__ E,
    const float* __restrict__ Wf, const float* __restrict__ bihf, const float* __restrict__ bhhf,
    const float* __restrict__ Wb, const float* __restrict__ bihb, const float* __restrict__ bhhb,
    float* __restrict__ xg_f, float* __restrict__ xg_b)
{
    __shared__ __align__(16) float xsh[8][D_DIM];
    __shared__ int sq[8];
    const int b = blockIdx.x, tb = b >> 3, cb = b & 7, j = threadIdx.x;
    if (j < 8) sq[j] = seq[tb*8 + j];
    __syncthreads();
    #pragma unroll
    for (int r = 0; r < 8; ++r) xsh[r][j] = E[(size_t)sq[r]*D_DIM + j];
    __syncthreads();
    const int col = cb*256 + j;      // 0..2047
    const int d   = col >> 10;       // 0 fwd, 1 bwd
    const int row = col & 1023;
    const float* W = d ? Wb : Wf;
    const float bias = d ? (bihb[row] + bhhb[row]) : (bihf[row] + bhhf[row]);
    const float4* wr = reinterpret_cast<const float4*>(W + (size_t)row*D_DIM);
    float acc[8];
    #pragma unroll
    for (int r=0;r<8;++r) acc[r] = 0.f;
    for (int kk = 0; kk < D_DIM/4; ++kk){
        float4 wv = wr[kk];
        #pragma unroll
        for (int r=0;r<8;++r){
            float4 xv = reinterpret_cast<const float4*>(xsh[r])[kk];
            acc[r] = fmaf(wv.x, xv.x, fmaf(wv.y, xv.y, fmaf(wv.z, xv.z, fmaf(wv.w, xv.w, acc[r]))));
        }
    }
    #pragma unroll
    for (int r=0;r<8;++r){
        const int t = tb*8 + r;
        const float v = acc[r] + bias;
        if (d == 0) xg_f[(size_t)t*G4 + row] = v;
        else        xg_b[(size_t)(T_LEN-1-t)*G4 + row] = v;
    }
}

// ---------------------------------------------------------------------------
// K2: bidirectional LSTM recurrence. 8 persistent blocks (dir x quarter),
// weights register-resident; matvec via v_pk_fma_f32 (2 MAC/instr, rounding
// order identical to the scalar 4-accumulator version).
// Cross-block h exchange: producers do relaxed-agent ATOMIC stores of packed
// (tag<<32|h_bits); consumers poll with COALESCED sc0/sc1 system-scope plain
// loads (the round-1 bottleneck was 64-per-wave uncoalesced atomic poll
// loads congesting the coherence point). Every 8th failed poll falls back to
// an atomic load as livelock insurance.
// ---------------------------------------------------------------------------
__global__ __launch_bounds__(256,1) void k_lstm(
    const float* __restrict__ Whh_f, const float* __restrict__ Whh_b,
    const float* __restrict__ xgf, const float* __restrict__ xgb,
    const float* __restrict__ h0, const float* __restrict__ c0,
    float* __restrict__ hs_f, float* __restrict__ hs_b,
    u64* __restrict__ hbuf_all)
{
    const int blk = blockIdx.x;
    const int d = blk >> 2, q = blk & 3;
    const int j = threadIdx.x;        // 0..255
    const int gi = j >> 6, uu = j & 63;
    const int row = gi*256 + q*64 + uu;          // gate row in [0,1024)
    const float* __restrict__ Whh = d ? Whh_b : Whh_f;
    const float* __restrict__ xg  = d ? xgb : xgf;
    float* __restrict__ hs = d ? hs_b : hs_f;
    u64* __restrict__ hb = hbuf_all + (size_t)d*2*HDIM;   // [parity][unit]

    __shared__ __align__(16) float h_sh[HDIM];
    __shared__ float g_sh[256];

    v2f wv2[128];                     // 256 VGPRs of weights (f32, packed pairs)
    {
        const v2f* wr = reinterpret_cast<const v2f*>(Whh + (size_t)row*HDIM);
        #pragma unroll
        for (int kk=0; kk<128; ++kk) wv2[kk] = wr[kk];
    }
    h_sh[j] = h0[d*HDIM + j];
    float c = (j < 64) ? c0[d*HDIM + q*64 + j] : 0.0f;
    float xgc = xg[row];              // xg[0][row]
    __syncthreads();

    const int ownlo = q*64, ownhi = q*64 + 64;
    for (int t = 0; t < T_LEN; ++t){
        // matvec: g_row = xg[t][row] + dot(Whh[row,:], h_{t-1})
        v2f accA = {0.f, 0.f}, accB = {0.f, 0.f};   // lanes: (x,y) and (z,w)
        const float4* h4 = reinterpret_cast<const float4*>(h_sh);
        #pragma unroll
        for (int kk=0;kk<64;++kk){
            float4 hv = h4[kk];
            v2f hlo; hlo.x = hv.x; hlo.y = hv.y;
            v2f hhi; hhi.x = hv.z; hhi.y = hv.w;
            asm("v_pk_fma_f32 %0, %1, %2, %0" : "+v"(accA) : "v"(wv2[2*kk]),   "v"(hlo));
            asm("v_pk_fma_f32 %0, %1, %2, %0" : "+v"(accB) : "v"(wv2[2*kk+1]), "v"(hhi));
        }
        g_sh[j] = xgc + ((accA.x+accA.y)+(accB.x+accB.y));
        {   // prefetch next step's xg
            const int tn = (t+1 < T_LEN) ? (t+1) : t;
            xgc = xg[(size_t)tn*G4 + row];
        }
        __syncthreads();              // B1: gates ready, h_sh reads done
        const int par = (t+1) & 1;
        if (j < 64){
            const int u = ownlo + j;
            const float ig = sigf(g_sh[j]);
            const float fg = sigf(g_sh[64+j]);
            const float gg = tanhf(g_sh[128+j]);
            const float og = sigf(g_sh[192+j]);
            c = fg*c + ig*gg;
            const float h = og*tanhf(c);
            const u64 pk = ((u64)(u32)(t+1) << 32) | (u64)__float_as_uint(h);
            __hip_atomic_store(&hb[par*HDIM + u], pk, __ATOMIC_RELAXED, __HIP_MEMORY_SCOPE_AGENT);
            h_sh[u] = h;
            hs[(size_t)(d==0 ? t : (T_LEN-1-t))*HDIM + u] = h;
        }
        if (t+1 < T_LEN){
            const int u = j;          // unit this thread waits for
            if (u < ownlo || u >= ownhi){
                const u32 want = (u32)(t+1);
                u64* p = &hb[par*HDIM + u];
                u64 pk;
                int it = 0;
                for (;;){
                    pk = ld_u64_sys(p);                 // coalesced coherent poll
                    if ((u32)(pk >> 32) == want) break;
                    if (((++it) & 7) == 0){             // livelock insurance
                        __builtin_amdgcn_s_sleep(1);
                        pk = __hip_atomic_load(p, __ATOMIC_RELAXED, __HIP_MEMORY_SCOPE_AGENT);
                        if ((u32)(pk >> 32) == want) break;
                    }
                }
                h_sh[u] = __uint_as_float((u32)pk);
            }
        }
        __syncthreads();              // B2: h_sh = h_t complete
    }
}

// ---------------------------------------------------------------------------
// K3: feats[t][tag] = [hf[t]; hb[t]] . W_out[tag] + b_out[tag]  (f64 accum)
// ---------------------------------------------------------------------------
__global__ __launch_bounds__(256) void k_feats(
    const float* __restrict__ hs_f, const float* __restrict__ hs_b,
    const float* __restrict__ W_out, const float* __restrict__ b_out,
    float* __restrict__ feats)
{
    __shared__ __align__(16) float fsh[8][512];
    const int tb = blockIdx.x, j = threadIdx.x;
    #pragma unroll
    for (int r=0;r<8;++r){
        const int t = tb*8 + r;
        fsh[r][j]       = hs_f[(size_t)t*HDIM + j];
        fsh[r][256 + j] = hs_b[(size_t)t*HDIM + j];
    }
    __syncthreads();
    const int tsub = j >> 5, tag = j & 31;
    const float4* wr = reinterpret_cast<const float4*>(W_out + (size_t)tag*512);
    double acc = (double)b_out[tag];
    for (int kk=0; kk<128; ++kk){
        float4 wvv = wr[kk];
        float4 hv = reinterpret_cast<const float4*>(fsh[tsub])[kk];
        acc += (double)wvv.x*hv.x + (double)wvv.y*hv.y + (double)wvv.z*hv.z + (double)wvv.w*hv.w;
    }
    feats[(size_t)(tb*8+tsub)*NTAGS + tag] = (float)acc;
}

// ---------------------------------------------------------------------------
// K4: Viterbi in f64, first-index tie rule matching np.argmax. Wave 0 scans;
// waves 1-3 double-buffer feat chunks. Then LDS-chunked serial backtrace.
// ---------------------------------------------------------------------------
__global__ __launch_bounds__(256,1) void k_viterbi(
    const float* __restrict__ feats, const float* __restrict__ trans,
    unsigned char* __restrict__ bp_g, float* __restrict__ out)
{
    __shared__ __align__(16) float fbuf[2][256*NTAGS];   // 2 x 32KB
    __shared__ double fv_sh[NTAGS];
    __shared__ double term_sh[NTAGS];
    __shared__ int best_sh;
    const int j = threadIdx.x;
    const int n = j & 31, ph = (j >> 5) & 1;
    const bool scanlane = (j < 64);
    double tr[16];
    if (scanlane){
        #pragma unroll
        for (int i=0;i<16;++i) tr[i] = (double)trans[n*NTAGS + ph*16 + i];
    }
    double fv = (n == START_TAG) ? 0.0 : -10000.0;

    const int CH = 256, NCH = T_LEN / CH;  // 16 chunks
    for (int idx = j; idx < CH*NTAGS; idx += 256) fbuf[0][idx] = feats[idx];
    __syncthreads();
    for (int cc = 0; cc < NCH; ++cc){
        const int buf = cc & 1;
        if (scanlane){
            for (int s = 0; s < CH; ++s){
                const int t = cc*CH + s;
                const float f = fbuf[buf][s*NTAGS + n];
                if (ph == 0) fv_sh[n] = fv;      // same-wave lockstep publish
                double bestv = -1e300; int bestp = 0;
                #pragma unroll
                for (int i=0;i<16;++i){
                    const int p = ph*16 + i;
                    const double v = fv_sh[p] + tr[i];
                    if (v > bestv){ bestv = v; bestp = p; }   // strict > = first index
                }
                const double ov = __shfl_xor(bestv, 32, 64);
                const int    op = __shfl_xor(bestp, 32, 64);
                const double lowv  = ph ? ov    : bestv;
                const int    lowp  = ph ? op    : bestp;
                const double highv = ph ? bestv : ov;
                const int    highp = ph ? bestp : op;
                double wvv = lowv; int wp = lowp;
                if (highv > lowv){ wvv = highv; wp = highp; } // low half wins ties
                if (ph == 0) bp_g[(size_t)t*NTAGS + n] = (unsigned char)wp;
                fv = wvv + (double)f;
            }
        } else if (cc + 1 < NCH){
            const int nb = (cc+1) & 1;
            const float* src = feats + (size_t)(cc+1)*CH*NTAGS;
            for (int idx = j - 64; idx < CH*NTAGS; idx += 192) fbuf[nb][idx] = src[idx];
        }
        __syncthreads();
    }

    if (scanlane && ph == 0) term_sh[n] = fv + (double)trans[STOP_TAG*NTAGS + n];
    __syncthreads();
    if (j == 0){
        double bv = term_sh[0]; int bi = 0;
        for (int p = 1; p < NTAGS; ++p){
            if (term_sh[p] > bv){ bv = term_sh[p]; bi = p; }
        }
        out[0] = (float)bv;
        out[1 + (T_LEN-1)] = (float)bi;
        best_sh = bi;
    }
    __threadfence();
    __syncthreads();
    // backtrace, 1024-step LDS chunks
    unsigned char* bp_sh = reinterpret_cast<unsigned char*>(fbuf);
    int b = best_sh;
    for (int cc2 = 3; cc2 >= 0; --cc2){
        const u32* src = reinterpret_cast<const u32*>(bp_g + (size_t)cc2*1024*NTAGS);
        u32* dst = reinterpret_cast<u32*>(bp_sh);
        for (int idx = j; idx < 8192; idx += 256) dst[idx] = src[idx];
        __syncthreads();
        if (j == 0){
            for (int tt = 1023; tt >= 0; --tt){
                const int t = cc2*1024 + tt;
                if (t == 0) break;                 // step into <START> dropped
                const int nb2 = bp_sh[tt*NTAGS + b];
                out[1 + (t-1)] = (float)nb2;
                b = nb2;
            }
        }
        __syncthreads();
    }
}

// ---------------------------------------------------------------------------
extern "C" void kernel_launch(void* const* d_in, const int* in_sizes, int n_in,
                              void* d_out, int out_size, void* d_ws, size_t ws_size,
                              hipStream_t stream)
{
    const int*   seq   = (const int*)  d_in[0];
    const float* E     = (const float*)d_in[1];
    const float* Wih_f = (const float*)d_in[2];
    const float* Whh_f = (const float*)d_in[3];
    const float* bih_f = (const float*)d_in[4];
    const float* bhh_f = (const float*)d_in[5];
    const float* Wih_b = (const float*)d_in[6];
    const float* Whh_b = (const float*)d_in[7];
    const float* bih_b = (const float*)d_in[8];
    const float* bhh_b = (const float*)d_in[9];
    const float* h0    = (const float*)d_in[10];
    const float* c0    = (const float*)d_in[11];
    const float* W_out = (const float*)d_in[12];
    const float* b_out = (const float*)d_in[13];
    const float* trans = (const float*)d_in[14];

    char* ws = (char*)d_ws;
    float* xg_f  = (float*)(ws);                                 // 16 MB
    float* xg_b  = (float*)(ws + (size_t)(16u<<20));             // 16 MB
    float* hs_f  = (float*)(ws + (size_t)(32u<<20));             // 4 MB
    float* hs_b  = (float*)(ws + (size_t)(36u<<20));             // 4 MB
    float* feats = (float*)(ws + (size_t)(40u<<20));             // 512 KB
    unsigned char* bp = (unsigned char*)(ws + (size_t)(40u<<20) + (512u<<10)); // 128 KB
    u64* hbuf    = (u64*)(ws + (size_t)(40u<<20) + (640u<<10));  // 8 KB

    k_xg<<<dim3(4096), dim3(256), 0, stream>>>(seq, E, Wih_f, bih_f, bhh_f,
                                               Wih_b, bih_b, bhh_b, xg_f, xg_b);
    k_lstm<<<dim3(8), dim3(256), 0, stream>>>(Whh_f, Whh_b, xg_f, xg_b, h0, c0, hs_f, hs_b, hbuf);
    k_feats<<<dim3(512), dim3(256), 0, stream>>>(hs_f, hs_b, W_out, b_out, feats);
    k_viterbi<<<dim3(1), dim3(256), 0, stream>>>(feats, trans, bp, (float*)d_out);
}

// Round 3
// 14788.129 us; speedup vs baseline: 1.0302x; 1.0302x over previous
//
#include <hip/hip_runtime.h>
#include <hip/hip_bf16.h>
#include <stdint.h>

#define T_LEN 4096
#define D_DIM 256
#define HDIM 256
#define G4 1024          // 4*HD gate rows per direction
#define NTAGS 32
#define START_TAG 30
#define STOP_TAG 31

typedef unsigned long long u64;
typedef unsigned int u32;
typedef float v2f __attribute__((ext_vector_type(2)));
typedef float v4f __attribute__((ext_vector_type(4)));

__device__ __forceinline__ float sigf(float x){ return 1.0f/(1.0f+expf(-x)); }

// ---------------------------------------------------------------------------
// K1: embedding gather + input projections xg = E[seq] @ Wih^T + (bih+bhh)
// ---------------------------------------------------------------------------
__global__ __launch_bounds__(256) void k_xg(const int* __restrict__ seq,
    const float* __restrict__ E,
    const float* __restrict__ Wf, const float* __restrict__ bihf, const float* __restrict__ bhhf,
    const float* __restrict__ Wb, const float* __restrict__ bihb, const float* __restrict__ bhhb,
    float* __restrict__ xg_f, float* __restrict__ xg_b)
{
    __shared__ __align__(16) float xsh[8][D_DIM];
    __shared__ int sq[8];
    const int b = blockIdx.x, tb = b >> 3, cb = b & 7, j = threadIdx.x;
    if (j < 8) sq[j] = seq[tb*8 + j];
    __syncthreads();
    #pragma unroll
    for (int r = 0; r < 8; ++r) xsh[r][j] = E[(size_t)sq[r]*D_DIM + j];
    __syncthreads();
    const int col = cb*256 + j;      // 0..2047
    const int d   = col >> 10;       // 0 fwd, 1 bwd
    const int row = col & 1023;
    const float* W = d ? Wb : Wf;
    const float bias = d ? (bihb[row] + bhhb[row]) : (bihf[row] + bhhf[row]);
    const float4* wr = reinterpret_cast<const float4*>(W + (size_t)row*D_DIM);
    float acc[8];
    #pragma unroll
    for (int r=0;r<8;++r) acc[r] = 0.f;
    for (int kk = 0; kk < D_DIM/4; ++kk){
        float4 wv = wr[kk];
        #pragma unroll
        for (int r=0;r<8;++r){
            float4 xv = reinterpret_cast<const float4*>(xsh[r])[kk];
            acc[r] = fmaf(wv.x, xv.x, fmaf(wv.y, xv.y, fmaf(wv.z, xv.z, fmaf(wv.w, xv.w, acc[r]))));
        }
    }
    #pragma unroll
    for (int r=0;r<8;++r){
        const int t = tb*8 + r;
        const float v = acc[r] + bias;
        if (d == 0) xg_f[(size_t)t*G4 + row] = v;
        else        xg_b[(size_t)(T_LEN-1-t)*G4 + row] = v;
    }
}

// ---------------------------------------------------------------------------
// K2: bidirectional LSTM recurrence. 8 persistent blocks (dir x quarter).
// r3 fixes:
//  (1) weights GENUINELY register-resident: laundered through opaque asm so
//      the compiler cannot rematerialize the global loads inside the t-loop
//      (r1/r2 VGPR_Count 184/144 proved weights were re-streamed from L2
//      every step: 256KB/step/CU ~= 4100 cy/step, the dominant cost).
//  (2) polls reverted to relaxed agent atomic loads (r1-proven), paced with
//      s_sleep(1) per miss to avoid LLC congestion from tight poll loops.
//  (3) matvec via v_pk_fma_f32, summation order identical to r1/r2
//      (absmax 0.0 verified) -> bit-identical h stream.
// ---------------------------------------------------------------------------
__global__ __launch_bounds__(256,1) void k_lstm(
    const float* __restrict__ Whh_f, const float* __restrict__ Whh_b,
    const float* __restrict__ xgf, const float* __restrict__ xgb,
    const float* __restrict__ h0, const float* __restrict__ c0,
    float* __restrict__ hs_f, float* __restrict__ hs_b,
    u64* __restrict__ hbuf_all)
{
    const int blk = blockIdx.x;
    const int d = blk >> 2, q = blk & 3;
    const int j = threadIdx.x;        // 0..255
    const int gi = j >> 6, uu = j & 63;
    const int row = gi*256 + q*64 + uu;          // gate row in [0,1024)
    const float* __restrict__ Whh = d ? Whh_b : Whh_f;
    const float* __restrict__ xg  = d ? xgb : xgf;
    float* __restrict__ hs = d ? hs_b : hs_f;
    u64* __restrict__ hb = hbuf_all + (size_t)d*2*HDIM;   // [parity][unit]

    __shared__ __align__(16) float h_sh[HDIM];
    __shared__ float g_sh[256];

    // ---- load weights and PIN them in VGPRs (launder defeats remat) ----
    v2f wv2[128];                     // 256 VGPRs of weights (f32 pairs)
    {
        const v2f* wr = reinterpret_cast<const v2f*>(Whh + (size_t)row*HDIM);
        #pragma unroll
        for (int kk=0; kk<128; ++kk) wv2[kk] = wr[kk];
    }
    #pragma unroll
    for (int kk=0; kk<128; ++kk){
        asm volatile("" : "+v"(wv2[kk]));   // opaque: value now non-rematerializable
    }

    h_sh[j] = h0[d*HDIM + j];
    float c = (j < 64) ? c0[d*HDIM + q*64 + j] : 0.0f;
    float xgc = xg[row];              // xg[0][row]
    __syncthreads();

    const int ownlo = q*64, ownhi = q*64 + 64;
    for (int t = 0; t < T_LEN; ++t){
        // matvec: g_row = xg[t][row] + dot(Whh[row,:], h_{t-1})
        v2f accA = {0.f, 0.f}, accB = {0.f, 0.f};   // k%4 lanes: (0,1) and (2,3)
        const v4f* h4 = reinterpret_cast<const v4f*>(h_sh);
        #pragma unroll
        for (int kk=0;kk<64;++kk){
            v4f hv = h4[kk];
            v2f hlo = hv.xy, hhi = hv.zw;           // swizzle: no repack movs
            asm("v_pk_fma_f32 %0, %1, %2, %0" : "+v"(accA) : "v"(wv2[2*kk]),   "v"(hlo));
            asm("v_pk_fma_f32 %0, %1, %2, %0" : "+v"(accB) : "v"(wv2[2*kk+1]), "v"(hhi));
        }
        g_sh[j] = xgc + ((accA.x+accA.y)+(accB.x+accB.y));
        {   // prefetch next step's xg
            const int tn = (t+1 < T_LEN) ? (t+1) : t;
            xgc = xg[(size_t)tn*G4 + row];
        }
        __syncthreads();              // B1: gates ready, h_sh reads done
        const int par = (t+1) & 1;
        if (j < 64){
            const int u = ownlo + j;
            const float ig = sigf(g_sh[j]);
            const float fg = sigf(g_sh[64+j]);
            const float gg = tanhf(g_sh[128+j]);
            const float og = sigf(g_sh[192+j]);
            c = fg*c + ig*gg;
            const float h = og*tanhf(c);
            const u64 pk = ((u64)(u32)(t+1) << 32) | (u64)__float_as_uint(h);
            __hip_atomic_store(&hb[par*HDIM + u], pk, __ATOMIC_RELAXED, __HIP_MEMORY_SCOPE_AGENT);
            h_sh[u] = h;
            hs[(size_t)(d==0 ? t : (T_LEN-1-t))*HDIM + u] = h;
        }
        if (t+1 < T_LEN){
            const int u = j;          // unit this thread waits for
            if (u < ownlo || u >= ownhi){
                const u32 want = (u32)(t+1);
                u64* p = &hb[par*HDIM + u];
                u64 pk = __hip_atomic_load(p, __ATOMIC_RELAXED, __HIP_MEMORY_SCOPE_AGENT);
                while ((u32)(pk >> 32) != want){
                    __builtin_amdgcn_s_sleep(1);    // pace: ~64cy backoff, no LLC hammering
                    pk = __hip_atomic_load(p, __ATOMIC_RELAXED, __HIP_MEMORY_SCOPE_AGENT);
                }
                h_sh[u] = __uint_as_float((u32)pk);
            }
        }
        __syncthreads();              // B2: h_sh = h_t complete
    }
}

// ---------------------------------------------------------------------------
// K3: feats[t][tag] = [hf[t]; hb[t]] . W_out[tag] + b_out[tag]  (f64 accum)
// ---------------------------------------------------------------------------
__global__ __launch_bounds__(256) void k_feats(
    const float* __restrict__ hs_f, const float* __restrict__ hs_b,
    const float* __restrict__ W_out, const float* __restrict__ b_out,
    float* __restrict__ feats)
{
    __shared__ __align__(16) float fsh[8][512];
    const int tb = blockIdx.x, j = threadIdx.x;
    #pragma unroll
    for (int r=0;r<8;++r){
        const int t = tb*8 + r;
        fsh[r][j]       = hs_f[(size_t)t*HDIM + j];
        fsh[r][256 + j] = hs_b[(size_t)t*HDIM + j];
    }
    __syncthreads();
    const int tsub = j >> 5, tag = j & 31;
    const float4* wr = reinterpret_cast<const float4*>(W_out + (size_t)tag*512);
    double acc = (double)b_out[tag];
    for (int kk=0; kk<128; ++kk){
        float4 wvv = wr[kk];
        float4 hv = reinterpret_cast<const float4*>(fsh[tsub])[kk];
        acc += (double)wvv.x*hv.x + (double)wvv.y*hv.y + (double)wvv.z*hv.z + (double)wvv.w*hv.w;
    }
    feats[(size_t)(tb*8+tsub)*NTAGS + tag] = (float)acc;
}

// ---------------------------------------------------------------------------
// K4: Viterbi in f64, first-index tie rule matching np.argmax. Wave 0 scans;
// waves 1-3 double-buffer feat chunks. Then LDS-chunked serial backtrace.
// ---------------------------------------------------------------------------
__global__ __launch_bounds__(256,1) void k_viterbi(
    const float* __restrict__ feats, const float* __restrict__ trans,
    unsigned char* __restrict__ bp_g, float* __restrict__ out)
{
    __shared__ __align__(16) float fbuf[2][256*NTAGS];   // 2 x 32KB
    __shared__ double fv_sh[NTAGS];
    __shared__ double term_sh[NTAGS];
    __shared__ int best_sh;
    const int j = threadIdx.x;
    const int n = j & 31, ph = (j >> 5) & 1;
    const bool scanlane = (j < 64);
    double tr[16];
    if (scanlane){
        #pragma unroll
        for (int i=0;i<16;++i) tr[i] = (double)trans[n*NTAGS + ph*16 + i];
    }
    double fv = (n == START_TAG) ? 0.0 : -10000.0;

    const int CH = 256, NCH = T_LEN / CH;  // 16 chunks
    for (int idx = j; idx < CH*NTAGS; idx += 256) fbuf[0][idx] = feats[idx];
    __syncthreads();
    for (int cc = 0; cc < NCH; ++cc){
        const int buf = cc & 1;
        if (scanlane){
            for (int s = 0; s < CH; ++s){
                const int t = cc*CH + s;
                const float f = fbuf[buf][s*NTAGS + n];
                if (ph == 0) fv_sh[n] = fv;      // same-wave lockstep publish
                double bestv = -1e300; int bestp = 0;
                #pragma unroll
                for (int i=0;i<16;++i){
                    const int p = ph*16 + i;
                    const double v = fv_sh[p] + tr[i];
                    if (v > bestv){ bestv = v; bestp = p; }   // strict > = first index
                }
                const double ov = __shfl_xor(bestv, 32, 64);
                const int    op = __shfl_xor(bestp, 32, 64);
                const double lowv  = ph ? ov    : bestv;
                const int    lowp  = ph ? op    : bestp;
                const double highv = ph ? bestv : ov;
                const int    highp = ph ? bestp : op;
                double wvv = lowv; int wp = lowp;
                if (highv > lowv){ wvv = highv; wp = highp; } // low half wins ties
                if (ph == 0) bp_g[(size_t)t*NTAGS + n] = (unsigned char)wp;
                fv = wvv + (double)f;
            }
        } else if (cc + 1 < NCH){
            const int nb = (cc+1) & 1;
            const float* src = feats + (size_t)(cc+1)*CH*NTAGS;
            for (int idx = j - 64; idx < CH*NTAGS; idx += 192) fbuf[nb][idx] = src[idx];
        }
        __syncthreads();
    }

    if (scanlane && ph == 0) term_sh[n] = fv + (double)trans[STOP_TAG*NTAGS + n];
    __syncthreads();
    if (j == 0){
        double bv = term_sh[0]; int bi = 0;
        for (int p = 1; p < NTAGS; ++p){
            if (term_sh[p] > bv){ bv = term_sh[p]; bi = p; }
        }
        out[0] = (float)bv;
        out[1 + (T_LEN-1)] = (float)bi;
        best_sh = bi;
    }
    __threadfence();
    __syncthreads();
    // backtrace, 1024-step LDS chunks
    unsigned char* bp_sh = reinterpret_cast<unsigned char*>(fbuf);
    int b = best_sh;
    for (int cc2 = 3; cc2 >= 0; --cc2){
        const u32* src = reinterpret_cast<const u32*>(bp_g + (size_t)cc2*1024*NTAGS);
        u32* dst = reinterpret_cast<u32*>(bp_sh);
        for (int idx = j; idx < 8192; idx += 256) dst[idx] = src[idx];
        __syncthreads();
        if (j == 0){
            for (int tt = 1023; tt >= 0; --tt){
                const int t = cc2*1024 + tt;
                if (t == 0) break;                 // step into <START> dropped
                const int nb2 = bp_sh[tt*NTAGS + b];
                out[1 + (t-1)] = (float)nb2;
                b = nb2;
            }
        }
        __syncthreads();
    }
}

// ---------------------------------------------------------------------------
extern "C" void kernel_launch(void* const* d_in, const int* in_sizes, int n_in,
                              void* d_out, int out_size, void* d_ws, size_t ws_size,
                              hipStream_t stream)
{
    const int*   seq   = (const int*)  d_in[0];
    const float* E     = (const float*)d_in[1];
    const float* Wih_f = (const float*)d_in[2];
    const float* Whh_f = (const float*)d_in[3];
    const float* bih_f = (const float*)d_in[4];
    const float* bhh_f = (const float*)d_in[5];
    const float* Wih_b = (const float*)d_in[6];
    const float* Whh_b = (const float*)d_in[7];
    const float* bih_b = (const float*)d_in[8];
    const float* bhh_b = (const float*)d_in[9];
    const float* h0    = (const float*)d_in[10];
    const float* c0    = (const float*)d_in[11];
    const float* W_out = (const float*)d_in[12];
    const float* b_out = (const float*)d_in[13];
    const float* trans = (const float*)d_in[14];

    char* ws = (char*)d_ws;
    float* xg_f  = (float*)(ws);                                 // 16 MB
    float* xg_b  = (float*)(ws + (size_t)(16u<<20));             // 16 MB
    float* hs_f  = (float*)(ws + (size_t)(32u<<20));             // 4 MB
    float* hs_b  = (float*)(ws + (size_t)(36u<<20));             // 4 MB
    float* feats = (float*)(ws + (size_t)(40u<<20));             // 512 KB
    unsigned char* bp = (unsigned char*)(ws + (size_t)(40u<<20) + (512u<<10)); // 128 KB
    u64* hbuf    = (u64*)(ws + (size_t)(40u<<20) + (640u<<10));  // 8 KB

    k_xg<<<dim3(4096), dim3(256), 0, stream>>>(seq, E, Wih_f, bih_f, bhh_f,
                                               Wih_b, bih_b, bhh_b, xg_f, xg_b);
    k_lstm<<<dim3(8), dim3(256), 0, stream>>>(Whh_f, Whh_b, xg_f, xg_b, h0, c0, hs_f, hs_b, hbuf);
    k_feats<<<dim3(512), dim3(256), 0, stream>>>(hs_f, hs_b, W_out, b_out, feats);
    k_viterbi<<<dim3(1), dim3(256), 0, stream>>>(feats, trans, bp, (float*)d_out);
}

// Round 4
// 8294.737 us; speedup vs baseline: 1.8367x; 1.7828x over previous
//
#include <hip/hip_runtime.h>
#include <hip/hip_bf16.h>
#include <stdint.h>

#define T_LEN 4096
#define D_DIM 256
#define HDIM 256
#define G4 1024          // 4*HD gate rows per direction
#define NTAGS 32
#define START_TAG 30
#define STOP_TAG 31

typedef unsigned long long u64;
typedef unsigned int u32;
typedef float v2f __attribute__((ext_vector_type(2)));
typedef float v4f __attribute__((ext_vector_type(4)));

__device__ __forceinline__ float sigf(float x){ return 1.0f/(1.0f+expf(-x)); }

// ---------------------------------------------------------------------------
// K1: embedding gather + input projections xg = E[seq] @ Wih^T + (bih+bhh)
// ---------------------------------------------------------------------------
__global__ __launch_bounds__(256) void k_xg(const int* __restrict__ seq,
    const float* __restrict__ E,
    const float* __restrict__ Wf, const float* __restrict__ bihf, const float* __restrict__ bhhf,
    const float* __restrict__ Wb, const float* __restrict__ bihb, const float* __restrict__ bhhb,
    float* __restrict__ xg_f, float* __restrict__ xg_b)
{
    __shared__ __align__(16) float xsh[8][D_DIM];
    __shared__ int sq[8];
    const int b = blockIdx.x, tb = b >> 3, cb = b & 7, j = threadIdx.x;
    if (j < 8) sq[j] = seq[tb*8 + j];
    __syncthreads();
    #pragma unroll
    for (int r = 0; r < 8; ++r) xsh[r][j] = E[(size_t)sq[r]*D_DIM + j];
    __syncthreads();
    const int col = cb*256 + j;      // 0..2047
    const int d   = col >> 10;       // 0 fwd, 1 bwd
    const int row = col & 1023;
    const float* W = d ? Wb : Wf;
    const float bias = d ? (bihb[row] + bhhb[row]) : (bihf[row] + bhhf[row]);
    const float4* wr = reinterpret_cast<const float4*>(W + (size_t)row*D_DIM);
    float acc[8];
    #pragma unroll
    for (int r=0;r<8;++r) acc[r] = 0.f;
    for (int kk = 0; kk < D_DIM/4; ++kk){
        float4 wv = wr[kk];
        #pragma unroll
        for (int r=0;r<8;++r){
            float4 xv = reinterpret_cast<const float4*>(xsh[r])[kk];
            acc[r] = fmaf(wv.x, xv.x, fmaf(wv.y, xv.y, fmaf(wv.z, xv.z, fmaf(wv.w, xv.w, acc[r]))));
        }
    }
    #pragma unroll
    for (int r=0;r<8;++r){
        const int t = tb*8 + r;
        const float v = acc[r] + bias;
        if (d == 0) xg_f[(size_t)t*G4 + row] = v;
        else        xg_b[(size_t)(T_LEN-1-t)*G4 + row] = v;
    }
}

// ---------------------------------------------------------------------------
// K2: bidirectional LSTM recurrence. 16 persistent blocks (dir x octant).
// r4 structural change: each gate row's K=256 dot is SPLIT ACROSS 2 THREADS
// (k-halves), so per-thread weight demand is 128 VGPRs (64 x v2f) instead of
// 256. r1-r3 proved the allocator spills/remats a 256-VGPR weight array
// (VGPR_Count 144-184, ~4100cy/step of L1 re-streaming); at ~180-200 total
// pressure it has no reason to spill. Halves combine via __shfl_xor(32)
// (pair lanes are in the same wave: wave=gate, bit5=half).
// Sync: r1-proven tight relaxed-agent atomic poll of packed (tag<<32|h).
// ---------------------------------------------------------------------------
__global__ __launch_bounds__(256,1) void k_lstm(
    const float* __restrict__ Whh_f, const float* __restrict__ Whh_b,
    const float* __restrict__ xgf, const float* __restrict__ xgb,
    const float* __restrict__ h0, const float* __restrict__ c0,
    float* __restrict__ hs_f, float* __restrict__ hs_b,
    u64* __restrict__ hbuf_all)
{
    const int blk = blockIdx.x;
    const int d = blk >> 3, oct = blk & 7;
    const int j = threadIdx.x;        // 0..255
    const int uu   = j & 31;          // unit offset within octant
    const int half = (j >> 5) & 1;    // k-half: 0 -> k[0,128), 1 -> k[128,256)
    const int gi   = j >> 6;          // gate index == wave id
    const int row_local  = gi*32 + uu;               // 0..127 (g_sh index)
    const int row_global = gi*256 + oct*32 + uu;     // gate row in [0,1024)
    const float* __restrict__ Whh = d ? Whh_b : Whh_f;
    const float* __restrict__ xg  = d ? xgb : xgf;
    float* __restrict__ hs = d ? hs_b : hs_f;
    u64* __restrict__ hb = hbuf_all + (size_t)d*2*HDIM;   // [parity][unit]

    __shared__ __align__(16) float h_sh[HDIM];
    __shared__ float g_sh[128];

    // ---- half-row of weights: 64 x v2f = 128 VGPRs, pinned via launder ----
    v2f w2[64];
    {
        const v2f* wr = reinterpret_cast<const v2f*>(Whh + (size_t)row_global*HDIM + half*128);
        #pragma unroll
        for (int kk=0; kk<64; ++kk) w2[kk] = wr[kk];
    }
    #pragma unroll
    for (int kk=0; kk<64; ++kk){
        asm volatile("" : "+v"(w2[kk]));    // non-rematerializable
    }

    h_sh[j] = h0[d*HDIM + j];
    const int ownlo = oct*32, ownhi = ownlo + 32;
    float c = (j < 32) ? c0[d*HDIM + ownlo + j] : 0.0f;
    float xgc = xg[row_global];       // xg[0][row] (same addr for both halves)
    __syncthreads();

    for (int t = 0; t < T_LEN; ++t){
        // half-dot: sum_k in my k-half of Whh[row,k]*h[k]
        v2f accA = {0.f, 0.f}, accB = {0.f, 0.f};
        const v4f* h4 = reinterpret_cast<const v4f*>(h_sh) + half*32;
        #pragma unroll
        for (int kk=0;kk<32;++kk){
            v4f hv = h4[kk];
            v2f hlo = hv.xy, hhi = hv.zw;
            asm("v_pk_fma_f32 %0, %1, %2, %0" : "+v"(accA) : "v"(w2[2*kk]),   "v"(hlo));
            asm("v_pk_fma_f32 %0, %1, %2, %0" : "+v"(accB) : "v"(w2[2*kk+1]), "v"(hhi));
        }
        const float partial = (accA.x+accA.y)+(accB.x+accB.y);
        const float other   = __shfl_xor(partial, 32, 64);   // partner half, same wave
        const float losum   = half ? other   : partial;
        const float hisum   = half ? partial : other;
        if (!half) g_sh[row_local] = xgc + (losum + hisum);
        {   // prefetch next step's xg
            const int tn = (t+1 < T_LEN) ? (t+1) : t;
            xgc = xg[(size_t)tn*G4 + row_global];
        }
        __syncthreads();              // B1: gates ready, h_sh reads done
        const int par = (t+1) & 1;
        if (j < 32){
            const float ig = sigf(g_sh[j]);
            const float fg = sigf(g_sh[32+j]);
            const float gg = tanhf(g_sh[64+j]);
            const float og = sigf(g_sh[96+j]);
            c = fg*c + ig*gg;
            const float h = og*tanhf(c);
            const int ug = ownlo + j;
            const u64 pk = ((u64)(u32)(t+1) << 32) | (u64)__float_as_uint(h);
            __hip_atomic_store(&hb[par*HDIM + ug], pk, __ATOMIC_RELAXED, __HIP_MEMORY_SCOPE_AGENT);
            h_sh[ug] = h;
            hs[(size_t)(d==0 ? t : (T_LEN-1-t))*HDIM + ug] = h;
        }
        if (t+1 < T_LEN){
            const int u = j;          // unit this thread waits for
            if (u < ownlo || u >= ownhi){
                const u32 want = (u32)(t+1);
                u64* p = &hb[par*HDIM + u];
                u64 pk = __hip_atomic_load(p, __ATOMIC_RELAXED, __HIP_MEMORY_SCOPE_AGENT);
                while ((u32)(pk >> 32) != want){
                    pk = __hip_atomic_load(p, __ATOMIC_RELAXED, __HIP_MEMORY_SCOPE_AGENT);
                }
                h_sh[u] = __uint_as_float((u32)pk);
            }
        }
        __syncthreads();              // B2: h_sh = h_t complete
    }
}

// ---------------------------------------------------------------------------
// K3: feats[t][tag] = [hf[t]; hb[t]] . W_out[tag] + b_out[tag]  (f64 accum)
// ---------------------------------------------------------------------------
__global__ __launch_bounds__(256) void k_feats(
    const float* __restrict__ hs_f, const float* __restrict__ hs_b,
    const float* __restrict__ W_out, const float* __restrict__ b_out,
    float* __restrict__ feats)
{
    __shared__ __align__(16) float fsh[8][512];
    const int tb = blockIdx.x, j = threadIdx.x;
    #pragma unroll
    for (int r=0;r<8;++r){
        const int t = tb*8 + r;
        fsh[r][j]       = hs_f[(size_t)t*HDIM + j];
        fsh[r][256 + j] = hs_b[(size_t)t*HDIM + j];
    }
    __syncthreads();
    const int tsub = j >> 5, tag = j & 31;
    const float4* wr = reinterpret_cast<const float4*>(W_out + (size_t)tag*512);
    double acc = (double)b_out[tag];
    for (int kk=0; kk<128; ++kk){
        float4 wvv = wr[kk];
        float4 hv = reinterpret_cast<const float4*>(fsh[tsub])[kk];
        acc += (double)wvv.x*hv.x + (double)wvv.y*hv.y + (double)wvv.z*hv.z + (double)wvv.w*hv.w;
    }
    feats[(size_t)(tb*8+tsub)*NTAGS + tag] = (float)acc;
}

// ---------------------------------------------------------------------------
// K4: Viterbi in f64, first-index tie rule matching np.argmax. Wave 0 scans;
// waves 1-3 double-buffer feat chunks. Then LDS-chunked serial backtrace.
// ---------------------------------------------------------------------------
__global__ __launch_bounds__(256,1) void k_viterbi(
    const float* __restrict__ feats, const float* __restrict__ trans,
    unsigned char* __restrict__ bp_g, float* __restrict__ out)
{
    __shared__ __align__(16) float fbuf[2][256*NTAGS];   // 2 x 32KB
    __shared__ double fv_sh[NTAGS];
    __shared__ double term_sh[NTAGS];
    __shared__ int best_sh;
    const int j = threadIdx.x;
    const int n = j & 31, ph = (j >> 5) & 1;
    const bool scanlane = (j < 64);
    double tr[16];
    if (scanlane){
        #pragma unroll
        for (int i=0;i<16;++i) tr[i] = (double)trans[n*NTAGS + ph*16 + i];
    }
    double fv = (n == START_TAG) ? 0.0 : -10000.0;

    const int CH = 256, NCH = T_LEN / CH;  // 16 chunks
    for (int idx = j; idx < CH*NTAGS; idx += 256) fbuf[0][idx] = feats[idx];
    __syncthreads();
    for (int cc = 0; cc < NCH; ++cc){
        const int buf = cc & 1;
        if (scanlane){
            for (int s = 0; s < CH; ++s){
                const int t = cc*CH + s;
                const float f = fbuf[buf][s*NTAGS + n];
                if (ph == 0) fv_sh[n] = fv;      // same-wave lockstep publish
                double bestv = -1e300; int bestp = 0;
                #pragma unroll
                for (int i=0;i<16;++i){
                    const int p = ph*16 + i;
                    const double v = fv_sh[p] + tr[i];
                    if (v > bestv){ bestv = v; bestp = p; }   // strict > = first index
                }
                const double ov = __shfl_xor(bestv, 32, 64);
                const int    op = __shfl_xor(bestp, 32, 64);
                const double lowv  = ph ? ov    : bestv;
                const int    lowp  = ph ? op    : bestp;
                const double highv = ph ? bestv : ov;
                const int    highp = ph ? bestp : op;
                double wvv = lowv; int wp = lowp;
                if (highv > lowv){ wvv = highv; wp = highp; } // low half wins ties
                if (ph == 0) bp_g[(size_t)t*NTAGS + n] = (unsigned char)wp;
                fv = wvv + (double)f;
            }
        } else if (cc + 1 < NCH){
            const int nb = (cc+1) & 1;
            const float* src = feats + (size_t)(cc+1)*CH*NTAGS;
            for (int idx = j - 64; idx < CH*NTAGS; idx += 192) fbuf[nb][idx] = src[idx];
        }
        __syncthreads();
    }

    if (scanlane && ph == 0) term_sh[n] = fv + (double)trans[STOP_TAG*NTAGS + n];
    __syncthreads();
    if (j == 0){
        double bv = term_sh[0]; int bi = 0;
        for (int p = 1; p < NTAGS; ++p){
            if (term_sh[p] > bv){ bv = term_sh[p]; bi = p; }
        }
        out[0] = (float)bv;
        out[1 + (T_LEN-1)] = (float)bi;
        best_sh = bi;
    }
    __threadfence();
    __syncthreads();
    // backtrace, 1024-step LDS chunks
    unsigned char* bp_sh = reinterpret_cast<unsigned char*>(fbuf);
    int b = best_sh;
    for (int cc2 = 3; cc2 >= 0; --cc2){
        const u32* src = reinterpret_cast<const u32*>(bp_g + (size_t)cc2*1024*NTAGS);
        u32* dst = reinterpret_cast<u32*>(bp_sh);
        for (int idx = j; idx < 8192; idx += 256) dst[idx] = src[idx];
        __syncthreads();
        if (j == 0){
            for (int tt = 1023; tt >= 0; --tt){
                const int t = cc2*1024 + tt;
                if (t == 0) break;                 // step into <START> dropped
                const int nb2 = bp_sh[tt*NTAGS + b];
                out[1 + (t-1)] = (float)nb2;
                b = nb2;
            }
        }
        __syncthreads();
    }
}

// ---------------------------------------------------------------------------
extern "C" void kernel_launch(void* const* d_in, const int* in_sizes, int n_in,
                              void* d_out, int out_size, void* d_ws, size_t ws_size,
                              hipStream_t stream)
{
    const int*   seq   = (const int*)  d_in[0];
    const float* E     = (const float*)d_in[1];
    const float* Wih_f = (const float*)d_in[2];
    const float* Whh_f = (const float*)d_in[3];
    const float* bih_f = (const float*)d_in[4];
    const float* bhh_f = (const float*)d_in[5];
    const float* Wih_b = (const float*)d_in[6];
    const float* Whh_b = (const float*)d_in[7];
    const float* bih_b = (const float*)d_in[8];
    const float* bhh_b = (const float*)d_in[9];
    const float* h0    = (const float*)d_in[10];
    const float* c0    = (const float*)d_in[11];
    const float* W_out = (const float*)d_in[12];
    const float* b_out = (const float*)d_in[13];
    const float* trans = (const float*)d_in[14];

    char* ws = (char*)d_ws;
    float* xg_f  = (float*)(ws);                                 // 16 MB
    float* xg_b  = (float*)(ws + (size_t)(16u<<20));             // 16 MB
    float* hs_f  = (float*)(ws + (size_t)(32u<<20));             // 4 MB
    float* hs_b  = (float*)(ws + (size_t)(36u<<20));             // 4 MB
    float* feats = (float*)(ws + (size_t)(40u<<20));             // 512 KB
    unsigned char* bp = (unsigned char*)(ws + (size_t)(40u<<20) + (512u<<10)); // 128 KB
    u64* hbuf    = (u64*)(ws + (size_t)(40u<<20) + (640u<<10));  // 8 KB

    k_xg<<<dim3(4096), dim3(256), 0, stream>>>(seq, E, Wih_f, bih_f, bhh_f,
                                               Wih_b, bih_b, bhh_b, xg_f, xg_b);
    k_lstm<<<dim3(16), dim3(256), 0, stream>>>(Whh_f, Whh_b, xg_f, xg_b, h0, c0, hs_f, hs_b, hbuf);
    k_feats<<<dim3(512), dim3(256), 0, stream>>>(hs_f, hs_b, W_out, b_out, feats);
    k_viterbi<<<dim3(1), dim3(256), 0, stream>>>(feats, trans, bp, (float*)d_out);
}